// Round 17
// baseline (289.839 us; speedup 1.0000x reference)
//
#include <hip/hip_runtime.h>

#define N_NODES   50000
#define N_EDGES   800000
#define HIDDEN    100
#define NUM_TASKS 128
#define NUM_GRAPHS 2000
#define EPS 1e-16f

typedef unsigned short u16;
typedef __attribute__((ext_vector_type(8))) short bf16x8;
typedef __attribute__((ext_vector_type(4))) float f32x4;

static __device__ __forceinline__ float rcp_fast(float v) {
    return __builtin_amdgcn_rcpf(v);  // 1-ulp v_rcp_f32
}
static __device__ __forceinline__ float invclip(float v) {
    // clip(v, EPS, 100) ** -1 : med3 = single-instruction clamp (finite inputs)
    return rcp_fast(__builtin_amdgcn_fmed3f(v, EPS, 100.0f));
}
static __device__ __forceinline__ unsigned pack_bf16x2(float a, float b) {
    unsigned r;
    asm("v_cvt_pk_bf16_f32 %0, %1, %2" : "=v"(r) : "v"(a), "v"(b));
    return r;  // low16 = bf16(a), high16 = bf16(b), RNE
}
static __device__ __forceinline__ float bf_lo(unsigned u) { return __int_as_float(u << 16); }
static __device__ __forceinline__ float bf_hi(unsigned u) { return __int_as_float(u & 0xFFFF0000u); }

// ================= fused prep: deg_count | encoder | wt =================
#define DEG_BLOCKS 3125    // 800000 / 256
#define ENC_BLOCKS 12500   // 50000 / 4 (4 nodes per 256-thr block)
#define WT_BLOCKS  56      // 2 * 112*64 entries / 256
__global__ __launch_bounds__(256) void prep_kernel(
        const int* __restrict__ col, int* __restrict__ deg,
        const int* __restrict__ x, const float* __restrict__ emb,
        unsigned* __restrict__ hb,
        const float* __restrict__ W1, const float* __restrict__ W2,
        unsigned* __restrict__ wt1, unsigned* __restrict__ wt2) {
    int b = blockIdx.x, t = threadIdx.x;
    if (b < DEG_BLOCKS) {
        int e = b * 256 + t;
        if (e < N_EDGES) atomicAdd(&deg[col[e]], 1);
    } else if (b < DEG_BLOCKS + ENC_BLOCKS) {
        int n = (b - DEG_BLOCKS) * 4 + (t >> 6);
        int lane = t & 63;
        if (lane < 50) {
            const int offs[9] = {0, 119, 124, 136, 148, 158, 164, 170, 172};
            float a0 = 0.f, a1 = 0.f;
#pragma unroll
            for (int f = 0; f < 9; ++f) {
                int idx = x[n * 9 + f] + offs[f];
                float2 v = *(const float2*)&emb[(size_t)idx * HIDDEN + 2 * lane];
                a0 += v.x; a1 += v.y;
            }
            hb[(size_t)n * 50 + lane] = pack_bf16x2(a0, a1);
        }
    } else {
        int e = (b - DEG_BLOCKS - ENC_BLOCKS) * 256 + t;  // 0..14335
        const float* W = (e < 7168) ? W1 : W2;
        unsigned* wt   = (e < 7168) ? wt1 : wt2;
        int idx = (e < 7168) ? e : e - 7168;
        int n = idx >> 6, tp = idx & 63, k = 2 * tp;
        float x0 = 0.f, x1 = 0.f;
        if (n < HIDDEN) {
            if (k < HIDDEN)     x0 = W[(size_t)k * HIDDEN + n];
            if (k + 1 < HIDDEN) x1 = W[(size_t)(k + 1) * HIDDEN + n];
        }
        wt[n * 64 + tp] = pack_bf16x2(x0, x1);
    }
}

// ---- per-block sums of raw deg ----
__global__ void blk_sum_kernel(const int* __restrict__ deg, int* __restrict__ bsum) {
    int i = blockIdx.x * 256 + threadIdx.x;
    int v = (i < N_NODES) ? deg[i] : 0;
#pragma unroll
    for (int off = 32; off > 0; off >>= 1) v += __shfl_down(v, off, 64);
    __shared__ int ws[4];
    if ((threadIdx.x & 63) == 0) ws[threadIdx.x >> 6] = v;
    __syncthreads();
    if (threadIdx.x == 0) bsum[blockIdx.x] = ws[0] + ws[1] + ws[2] + ws[3];
}

// ---- blk_scan with fused bsum-prefix + dinv + cursor zeroing ----
#define SCAN_BLOCKS 196
__global__ void blk_scan_kernel(const int* __restrict__ deg, const int* __restrict__ bsum,
                                int* __restrict__ csr_off, float* __restrict__ dinv,
                                int* __restrict__ cursor) {
    __shared__ int sb[256];
    __shared__ int buf[256];
    int t = threadIdx.x;
    sb[t] = (t < SCAN_BLOCKS) ? bsum[t] : 0;
    __syncthreads();
    for (int off = 1; off < 256; off <<= 1) {
        int v = (t >= off) ? sb[t - off] : 0;
        __syncthreads();
        sb[t] += v;
        __syncthreads();
    }
    int mine = (blockIdx.x < SCAN_BLOCKS) ? bsum[blockIdx.x] : 0;
    int base = sb[blockIdx.x] - mine;  // exclusive prefix for this block

    int i = blockIdx.x * 256 + t;
    int dv = (i < N_NODES) ? deg[i] : 0;
    buf[t] = dv;
    __syncthreads();
    for (int off = 1; off < 256; off <<= 1) {
        int v = (t >= off) ? buf[t - off] : 0;
        __syncthreads();
        buf[t] += v;
        __syncthreads();
    }
    if (i < N_NODES) {
        csr_off[i] = base + buf[t] - dv;
        dinv[i] = 1.0f / sqrtf((float)(dv + 1));
        cursor[i] = 0;
    } else if (i == N_NODES) {
        csr_off[N_NODES] = N_EDGES;
    }
}

// ---- counting-sort edges by target; pack (src, norm) per slot ----
__global__ void scatter_kernel(const int* __restrict__ row, const int* __restrict__ col,
                               const int* __restrict__ csr_off, int* __restrict__ cursor,
                               const float* __restrict__ dinv, int2* __restrict__ csr_pack) {
    int e = blockIdx.x * blockDim.x + threadIdx.x;
    if (e >= N_EDGES) return;
    int s = row[e], d = col[e];
    int pos = csr_off[d] + atomicAdd(&cursor[d], 1);
    int2 p;
    p.x = s;
    p.y = __float_as_int(dinv[s] * dinv[d]);
    csr_pack[pos] = p;
}

// ---- MFMA bf16 GEMM: 4 tiles per block, Bt staged once, pad zeroed once ----
#define MMB     64
#define LDSK    152
#define MMGRID  196   // 196*4 = 784 >= 782 tiles
__global__ __launch_bounds__(256) void mfma_matmul_kernel(
        const unsigned* __restrict__ inb, const unsigned* __restrict__ wt,
        u16* __restrict__ outh) {
    __shared__ u16 A_l[MMB * LDSK];
    __shared__ u16 Bt_l[112 * LDSK];
    int tid = threadIdx.x;

    // stage Bt once (112 rows x 32 uint2, coalesced L2 hits)
    {
        const uint2* wt2v = (const uint2*)wt;
        for (int i = tid; i < 112 * 32; i += 256) {
            int n = i >> 5, j = i & 31;
            *(uint2*)&Bt_l[n * LDSK + 4 * j] = wt2v[i];
        }
    }
    // zero A pad region k=100..127 once (persists across tiles)
    for (int i = tid; i < MMB * 7; i += 256) {
        int n = i / 7, j = i % 7;
        *(uint2*)&A_l[n * LDSK + 100 + 4 * j] = make_uint2(0u, 0u);
    }

    int w = tid >> 6, l = tid & 63;
    int mrow = 16 * w + (l & 15);
    int koff = (l >> 4) * 8;
    int mbase = 16 * w + (l >> 4) * 4;

#pragma unroll
    for (int tt = 0; tt < 4; ++tt) {
        int nb = (blockIdx.x + tt * MMGRID) * MMB;
        if (nb >= N_NODES) break;   // block-uniform

        for (int i = tid; i < MMB * 25; i += 256) {
            int n = i / 25, j = i % 25;
            uint2 v = make_uint2(0u, 0u);
            if (nb + n < N_NODES) v = *(const uint2*)&inb[(size_t)(nb + n) * 50 + 2 * j];
            *(uint2*)&A_l[n * LDSK + 4 * j] = v;
        }
        __syncthreads();

        f32x4 acc[7];
#pragma unroll
        for (int t = 0; t < 7; ++t) acc[t] = (f32x4){0.f, 0.f, 0.f, 0.f};

#pragma unroll
        for (int ks = 0; ks < 4; ++ks) {
            int k0 = 32 * ks + koff;
            bf16x8 a = *(const bf16x8*)&A_l[mrow * LDSK + k0];
#pragma unroll
            for (int t = 0; t < 7; ++t) {
                bf16x8 b = *(const bf16x8*)&Bt_l[(16 * t + (l & 15)) * LDSK + k0];
                acc[t] = __builtin_amdgcn_mfma_f32_16x16x32_bf16(a, b, acc[t], 0, 0, 0);
            }
        }

        // direct bf16 stores (C/D map m89: col=lane&15, row=(lane>>4)*4+reg)
#pragma unroll
        for (int t = 0; t < 7; ++t) {
#pragma unroll
            for (int r = 0; r < 4; ++r) {
                int m = mbase + r;
                if (nb + m < N_NODES) {
                    unsigned p = pack_bf16x2(acc[t][r], acc[t][r]);
                    outh[(size_t)(nb + m) * HIDDEN + 16 * t + (l & 15)] = (u16)p;
                }
            }
        }
        __syncthreads();  // A_l safe to restage next tile
    }
}

// ---- GCN aggregation (proven config): wave per node, bf16x2 gathers ----
__global__ __launch_bounds__(256) void agg_kernel(
        const unsigned* __restrict__ hw16, const int* __restrict__ csr_off,
        const int2* __restrict__ csr_pack, const float* __restrict__ dinv,
        const int* __restrict__ deg, const float* __restrict__ bias,
        unsigned* __restrict__ out16, int relu) {
    int wid  = (blockIdx.x * blockDim.x + threadIdx.x) >> 6;
    int lane = threadIdx.x & 63;
    if (wid >= N_NODES) return;
    int n = wid;
    bool act = lane < 50;  // lane owns dims 2*lane (low16), 2*lane+1 (high16)

    float cnt = (float)(deg[n] + 1);  // raw in-degree + self-loop
    float dn  = dinv[n];
    float nrm = dn * dn;  // self-loop norm

    float2 acc = make_float2(0.f, 0.f);
    if (act) {
        unsigned u = hw16[(size_t)n * 50 + lane];
        acc.x = invclip(nrm * bf_lo(u));
        acc.y = invclip(nrm * bf_hi(u));
    }

    int beg = csr_off[n], end = csr_off[n + 1];
    int i = beg;
    for (; i + 4 <= end; i += 4) {
        int2 p0 = csr_pack[i];
        int2 p1 = csr_pack[i + 1];
        int2 p2 = csr_pack[i + 2];
        int2 p3 = csr_pack[i + 3];
        unsigned u0 = act ? hw16[(size_t)p0.x * 50 + lane] : 0u;
        unsigned u1 = act ? hw16[(size_t)p1.x * 50 + lane] : 0u;
        unsigned u2 = act ? hw16[(size_t)p2.x * 50 + lane] : 0u;
        unsigned u3 = act ? hw16[(size_t)p3.x * 50 + lane] : 0u;
        float w0 = __int_as_float(p0.y), w1 = __int_as_float(p1.y);
        float w2 = __int_as_float(p2.y), w3 = __int_as_float(p3.y);
        acc.x += invclip(w0 * bf_lo(u0)); acc.y += invclip(w0 * bf_hi(u0));
        acc.x += invclip(w1 * bf_lo(u1)); acc.y += invclip(w1 * bf_hi(u1));
        acc.x += invclip(w2 * bf_lo(u2)); acc.y += invclip(w2 * bf_hi(u2));
        acc.x += invclip(w3 * bf_lo(u3)); acc.y += invclip(w3 * bf_hi(u3));
    }
    for (; i < end; ++i) {
        int2 p = csr_pack[i];
        unsigned u = act ? hw16[(size_t)p.x * 50 + lane] : 0u;
        float w = __int_as_float(p.y);
        acc.x += invclip(w * bf_lo(u));
        acc.y += invclip(w * bf_hi(u));
    }

    if (act) {
        float rcnt = rcp_fast(cnt);
        float ox = invclip(acc.x * rcnt) + bias[2 * lane];
        float oy = invclip(acc.y * rcnt) + bias[2 * lane + 1];
        if (relu) { ox = fmaxf(ox, 0.f); oy = fmaxf(oy, 0.f); }
        out16[(size_t)n * 50 + lane] = pack_bf16x2(ox, oy);
    }
}

// ---- fused mean-pool + linear head: 2 graphs per 256-thr block ----
__global__ __launch_bounds__(256) void pool_final_kernel(
        const unsigned* __restrict__ hb, const int* __restrict__ batch,
        const float* __restrict__ Wlin, const float* __restrict__ blin,
        float* __restrict__ out) {
    int half = threadIdx.x >> 7;           // waves 0-1 -> graph g0, waves 2-3 -> g1
    int t    = threadIdx.x & 127;
    int g    = blockIdx.x * 2 + half;
    __shared__ float pl[2][HIDDEN];

    if (g < NUM_GRAPHS) {
        int lo = 0, hi = N_NODES;
        while (lo < hi) { int mid = (lo + hi) >> 1; if (batch[mid] < g) lo = mid + 1; else hi = mid; }
        int start = lo;
        hi = N_NODES;
        while (lo < hi) { int mid = (lo + hi) >> 1; if (batch[mid] < g + 1) lo = mid + 1; else hi = mid; }
        int end = lo;

        float inv = 1.0f / fmaxf((float)(end - start), 1.0f);
        if (t < 50) {
            float a0 = 0.f, a1 = 0.f;
            for (int n = start; n < end; ++n) {
                unsigned u = hb[(size_t)n * 50 + t];
                a0 += bf_lo(u); a1 += bf_hi(u);
            }
            pl[half][2 * t]     = a0 * inv;
            pl[half][2 * t + 1] = a1 * inv;
        }
    }
    __syncthreads();

    if (g < NUM_GRAPHS) {
        float o = 0.f;
#pragma unroll 4
        for (int j = 0; j < HIDDEN; ++j) o += pl[half][j] * Wlin[j * NUM_TASKS + t];
        out[(size_t)g * NUM_TASKS + t] = o + blin[t];
    }
}

extern "C" void kernel_launch(void* const* d_in, const int* in_sizes, int n_in,
                              void* d_out, int out_size, void* d_ws, size_t ws_size,
                              hipStream_t stream) {
    const int*   x     = (const int*)d_in[0];
    const int*   ei    = (const int*)d_in[1];
    const int*   batch = (const int*)d_in[2];
    const float* emb   = (const float*)d_in[3];
    const float* W1    = (const float*)d_in[4];
    const float* b1    = (const float*)d_in[5];
    const float* W2    = (const float*)d_in[6];
    const float* b2    = (const float*)d_in[7];
    const float* Wlin  = (const float*)d_in[8];
    const float* blin  = (const float*)d_in[9];
    float* out = (float*)d_out;

    const int* row = ei;             // edge_index[0] = source
    const int* col = ei + N_EDGES;   // edge_index[1] = target

    char* ws = (char*)d_ws;
    auto alloc = [&](size_t bytes) -> char* {
        char* p = ws;
        ws += (bytes + 255) & ~(size_t)255;
        return p;
    };
    int*      deg      = (int*)     alloc((size_t)N_NODES * 4);
    int*      cursor   = (int*)     alloc((size_t)N_NODES * 4);
    int*      csr_off  = (int*)     alloc((size_t)(N_NODES + 1) * 4);
    float*    dinv     = (float*)   alloc((size_t)N_NODES * 4);
    int2*     csr_pack = (int2*)    alloc((size_t)N_EDGES * 8);
    unsigned* bufP     = (unsigned*)alloc((size_t)N_NODES * 50 * 4);  // packed h0/h1/h2
    unsigned* hw16     = (unsigned*)alloc((size_t)N_NODES * 50 * 4);  // packed hw
    unsigned* wt1      = (unsigned*)alloc(112 * 64 * 4);              // bf16 W1^T tile
    unsigned* wt2      = (unsigned*)alloc(112 * 64 * 4);              // bf16 W2^T tile
    int*      bsum     = (int*)     alloc(256 * 4);

    hipMemsetAsync(deg, 0, (size_t)N_NODES * 4, stream);
    prep_kernel<<<DEG_BLOCKS + ENC_BLOCKS + WT_BLOCKS, 256, 0, stream>>>(
        col, deg, x, emb, bufP, W1, W2, wt1, wt2);
    blk_sum_kernel<<<SCAN_BLOCKS, 256, 0, stream>>>(deg, bsum);
    blk_scan_kernel<<<SCAN_BLOCKS, 256, 0, stream>>>(deg, bsum, csr_off, dinv, cursor);
    scatter_kernel<<<(N_EDGES + 255) / 256, 256, 0, stream>>>(row, col, csr_off, cursor, dinv,
                                                              csr_pack);

    // conv1: hw = bf16(h0 @ W1); agg -> relu -> h1 (packed bf16)
    mfma_matmul_kernel<<<MMGRID, 256, 0, stream>>>(bufP, wt1, (u16*)hw16);
    agg_kernel<<<(N_NODES + 3) / 4, 256, 0, stream>>>(hw16, csr_off, csr_pack,
                                                      dinv, deg, b1, bufP, 1);
    // conv2: hw = bf16(h1 @ W2); agg -> h2 (packed bf16)
    mfma_matmul_kernel<<<MMGRID, 256, 0, stream>>>(bufP, wt2, (u16*)hw16);
    agg_kernel<<<(N_NODES + 3) / 4, 256, 0, stream>>>(hw16, csr_off, csr_pack,
                                                      dinv, deg, b2, bufP, 0);

    pool_final_kernel<<<(NUM_GRAPHS + 1) / 2, 256, 0, stream>>>(bufP, batch, Wlin, blin, out);
}

// Round 18
// 275.720 us; speedup vs baseline: 1.0512x; 1.0512x over previous
//
#include <hip/hip_runtime.h>

#define N_NODES   50000
#define N_EDGES   800000
#define HIDDEN    100
#define NUM_TASKS 128
#define NUM_GRAPHS 2000
#define EPS 1e-16f

typedef unsigned short u16;
typedef __attribute__((ext_vector_type(8))) short bf16x8;
typedef __attribute__((ext_vector_type(4))) float f32x4;

static __device__ __forceinline__ float rcp_fast(float v) {
    return __builtin_amdgcn_rcpf(v);  // 1-ulp v_rcp_f32
}
static __device__ __forceinline__ float invclip(float v) {
    // clip(v, EPS, 100) ** -1 : med3 = single-instruction clamp (finite inputs)
    return rcp_fast(__builtin_amdgcn_fmed3f(v, EPS, 100.0f));
}
static __device__ __forceinline__ unsigned pack_bf16x2(float a, float b) {
    unsigned r;
    asm("v_cvt_pk_bf16_f32 %0, %1, %2" : "=v"(r) : "v"(a), "v"(b));
    return r;  // low16 = bf16(a), high16 = bf16(b), RNE
}
static __device__ __forceinline__ float bf_lo(unsigned u) { return __int_as_float(u << 16); }
static __device__ __forceinline__ float bf_hi(unsigned u) { return __int_as_float(u & 0xFFFF0000u); }

// ================= fused prep: deg_count | encoder | wt =================
#define DEG_BLOCKS 3125    // 800000 / 256
#define ENC_BLOCKS 12500   // 50000 / 4 (4 nodes per 256-thr block)
#define WT_BLOCKS  56      // 2 * 112*64 entries / 256
__global__ __launch_bounds__(256) void prep_kernel(
        const int* __restrict__ col, int* __restrict__ deg,
        const int* __restrict__ x, const float* __restrict__ emb,
        unsigned* __restrict__ hb,
        const float* __restrict__ W1, const float* __restrict__ W2,
        unsigned* __restrict__ wt1, unsigned* __restrict__ wt2) {
    int b = blockIdx.x, t = threadIdx.x;
    if (b < DEG_BLOCKS) {
        int e = b * 256 + t;
        if (e < N_EDGES) atomicAdd(&deg[col[e]], 1);
    } else if (b < DEG_BLOCKS + ENC_BLOCKS) {
        int n = (b - DEG_BLOCKS) * 4 + (t >> 6);
        int lane = t & 63;
        if (lane < 50) {
            const int offs[9] = {0, 119, 124, 136, 148, 158, 164, 170, 172};
            float a0 = 0.f, a1 = 0.f;
#pragma unroll
            for (int f = 0; f < 9; ++f) {
                int idx = x[n * 9 + f] + offs[f];
                float2 v = *(const float2*)&emb[(size_t)idx * HIDDEN + 2 * lane];
                a0 += v.x; a1 += v.y;
            }
            hb[(size_t)n * 50 + lane] = pack_bf16x2(a0, a1);
        }
    } else {
        int e = (b - DEG_BLOCKS - ENC_BLOCKS) * 256 + t;  // 0..14335
        const float* W = (e < 7168) ? W1 : W2;
        unsigned* wt   = (e < 7168) ? wt1 : wt2;
        int idx = (e < 7168) ? e : e - 7168;
        int n = idx >> 6, tp = idx & 63, k = 2 * tp;
        float x0 = 0.f, x1 = 0.f;
        if (n < HIDDEN) {
            if (k < HIDDEN)     x0 = W[(size_t)k * HIDDEN + n];
            if (k + 1 < HIDDEN) x1 = W[(size_t)(k + 1) * HIDDEN + n];
        }
        wt[n * 64 + tp] = pack_bf16x2(x0, x1);
    }
}

// ---- per-block sums of raw deg ----
__global__ void blk_sum_kernel(const int* __restrict__ deg, int* __restrict__ bsum) {
    int i = blockIdx.x * 256 + threadIdx.x;
    int v = (i < N_NODES) ? deg[i] : 0;
#pragma unroll
    for (int off = 32; off > 0; off >>= 1) v += __shfl_down(v, off, 64);
    __shared__ int ws[4];
    if ((threadIdx.x & 63) == 0) ws[threadIdx.x >> 6] = v;
    __syncthreads();
    if (threadIdx.x == 0) bsum[blockIdx.x] = ws[0] + ws[1] + ws[2] + ws[3];
}

// ---- blk_scan with fused bsum-prefix + dinv + cursor zeroing ----
#define SCAN_BLOCKS 196
__global__ void blk_scan_kernel(const int* __restrict__ deg, const int* __restrict__ bsum,
                                int* __restrict__ csr_off, float* __restrict__ dinv,
                                int* __restrict__ cursor) {
    __shared__ int sb[256];
    __shared__ int buf[256];
    int t = threadIdx.x;
    sb[t] = (t < SCAN_BLOCKS) ? bsum[t] : 0;
    __syncthreads();
    for (int off = 1; off < 256; off <<= 1) {
        int v = (t >= off) ? sb[t - off] : 0;
        __syncthreads();
        sb[t] += v;
        __syncthreads();
    }
    int mine = (blockIdx.x < SCAN_BLOCKS) ? bsum[blockIdx.x] : 0;
    int base = sb[blockIdx.x] - mine;  // exclusive prefix for this block

    int i = blockIdx.x * 256 + t;
    int dv = (i < N_NODES) ? deg[i] : 0;
    buf[t] = dv;
    __syncthreads();
    for (int off = 1; off < 256; off <<= 1) {
        int v = (t >= off) ? buf[t - off] : 0;
        __syncthreads();
        buf[t] += v;
        __syncthreads();
    }
    if (i < N_NODES) {
        csr_off[i] = base + buf[t] - dv;
        dinv[i] = 1.0f / sqrtf((float)(dv + 1));
        cursor[i] = 0;
    } else if (i == N_NODES) {
        csr_off[N_NODES] = N_EDGES;
    }
}

// ---- counting-sort edges by target; pack (src, norm) per slot ----
__global__ void scatter_kernel(const int* __restrict__ row, const int* __restrict__ col,
                               const int* __restrict__ csr_off, int* __restrict__ cursor,
                               const float* __restrict__ dinv, int2* __restrict__ csr_pack) {
    int e = blockIdx.x * blockDim.x + threadIdx.x;
    if (e >= N_EDGES) return;
    int s = row[e], d = col[e];
    int pos = csr_off[d] + atomicAdd(&cursor[d], 1);
    int2 p;
    p.x = s;
    p.y = __float_as_int(dinv[s] * dinv[d]);
    csr_pack[pos] = p;
}

// ---- MFMA bf16 GEMM (R16-proven): 2 tiles/block, Bt staged once, direct stores ----
#define MMB     64
#define LDSK    152
#define MMGRID  391   // 391*2 = 782 tiles; grid >= 256 CUs
__global__ __launch_bounds__(256) void mfma_matmul_kernel(
        const unsigned* __restrict__ inb, const unsigned* __restrict__ wt,
        u16* __restrict__ outh) {
    __shared__ u16 A_l[MMB * LDSK];
    __shared__ u16 Bt_l[112 * LDSK];
    int tid = threadIdx.x;

    // stage Bt once (112 rows x 32 uint2, coalesced L2 hits)
    {
        const uint2* wt2v = (const uint2*)wt;
        for (int i = tid; i < 112 * 32; i += 256) {
            int n = i >> 5, j = i & 31;
            *(uint2*)&Bt_l[n * LDSK + 4 * j] = wt2v[i];
        }
    }
    // zero A pad region k=100..127 once (persists across both tiles)
    for (int i = tid; i < MMB * 7; i += 256) {
        int n = i / 7, j = i % 7;
        *(uint2*)&A_l[n * LDSK + 100 + 4 * j] = make_uint2(0u, 0u);
    }

    int w = tid >> 6, l = tid & 63;
    int mrow = 16 * w + (l & 15);
    int koff = (l >> 4) * 8;
    int mbase = 16 * w + (l >> 4) * 4;

#pragma unroll
    for (int tt = 0; tt < 2; ++tt) {
        int nb = (blockIdx.x + tt * MMGRID) * MMB;

        // stage A (dims 0..99)
        for (int i = tid; i < MMB * 25; i += 256) {
            int n = i / 25, j = i % 25;
            uint2 v = make_uint2(0u, 0u);
            if (nb + n < N_NODES) v = *(const uint2*)&inb[(size_t)(nb + n) * 50 + 2 * j];
            *(uint2*)&A_l[n * LDSK + 4 * j] = v;
        }
        __syncthreads();

        f32x4 acc[7];
#pragma unroll
        for (int t = 0; t < 7; ++t) acc[t] = (f32x4){0.f, 0.f, 0.f, 0.f};

#pragma unroll
        for (int ks = 0; ks < 4; ++ks) {
            int k0 = 32 * ks + koff;
            bf16x8 a = *(const bf16x8*)&A_l[mrow * LDSK + k0];
#pragma unroll
            for (int t = 0; t < 7; ++t) {
                bf16x8 b = *(const bf16x8*)&Bt_l[(16 * t + (l & 15)) * LDSK + k0];
                acc[t] = __builtin_amdgcn_mfma_f32_16x16x32_bf16(a, b, acc[t], 0, 0, 0);
            }
        }

        // direct bf16 stores (C/D map m89: col=lane&15, row=(lane>>4)*4+reg)
#pragma unroll
        for (int t = 0; t < 7; ++t) {
#pragma unroll
            for (int r = 0; r < 4; ++r) {
                int m = mbase + r;
                if (nb + m < N_NODES) {
                    unsigned p = pack_bf16x2(acc[t][r], acc[t][r]);
                    outh[(size_t)(nb + m) * HIDDEN + 16 * t + (l & 15)] = (u16)p;
                }
            }
        }
        __syncthreads();  // A_l safe to restage next tile
    }
}

// ---- GCN aggregation (proven config): wave per node, bf16x2 gathers ----
__global__ __launch_bounds__(256) void agg_kernel(
        const unsigned* __restrict__ hw16, const int* __restrict__ csr_off,
        const int2* __restrict__ csr_pack, const float* __restrict__ dinv,
        const int* __restrict__ deg, const float* __restrict__ bias,
        unsigned* __restrict__ out16, int relu) {
    int wid  = (blockIdx.x * blockDim.x + threadIdx.x) >> 6;
    int lane = threadIdx.x & 63;
    if (wid >= N_NODES) return;
    int n = wid;
    bool act = lane < 50;  // lane owns dims 2*lane (low16), 2*lane+1 (high16)

    float cnt = (float)(deg[n] + 1);  // raw in-degree + self-loop
    float dn  = dinv[n];
    float nrm = dn * dn;  // self-loop norm

    float2 acc = make_float2(0.f, 0.f);
    if (act) {
        unsigned u = hw16[(size_t)n * 50 + lane];
        acc.x = invclip(nrm * bf_lo(u));
        acc.y = invclip(nrm * bf_hi(u));
    }

    int beg = csr_off[n], end = csr_off[n + 1];
    int i = beg;
    for (; i + 4 <= end; i += 4) {
        int2 p0 = csr_pack[i];
        int2 p1 = csr_pack[i + 1];
        int2 p2 = csr_pack[i + 2];
        int2 p3 = csr_pack[i + 3];
        unsigned u0 = act ? hw16[(size_t)p0.x * 50 + lane] : 0u;
        unsigned u1 = act ? hw16[(size_t)p1.x * 50 + lane] : 0u;
        unsigned u2 = act ? hw16[(size_t)p2.x * 50 + lane] : 0u;
        unsigned u3 = act ? hw16[(size_t)p3.x * 50 + lane] : 0u;
        float w0 = __int_as_float(p0.y), w1 = __int_as_float(p1.y);
        float w2 = __int_as_float(p2.y), w3 = __int_as_float(p3.y);
        acc.x += invclip(w0 * bf_lo(u0)); acc.y += invclip(w0 * bf_hi(u0));
        acc.x += invclip(w1 * bf_lo(u1)); acc.y += invclip(w1 * bf_hi(u1));
        acc.x += invclip(w2 * bf_lo(u2)); acc.y += invclip(w2 * bf_hi(u2));
        acc.x += invclip(w3 * bf_lo(u3)); acc.y += invclip(w3 * bf_hi(u3));
    }
    for (; i < end; ++i) {
        int2 p = csr_pack[i];
        unsigned u = act ? hw16[(size_t)p.x * 50 + lane] : 0u;
        float w = __int_as_float(p.y);
        acc.x += invclip(w * bf_lo(u));
        acc.y += invclip(w * bf_hi(u));
    }

    if (act) {
        float rcnt = rcp_fast(cnt);
        float ox = invclip(acc.x * rcnt) + bias[2 * lane];
        float oy = invclip(acc.y * rcnt) + bias[2 * lane + 1];
        if (relu) { ox = fmaxf(ox, 0.f); oy = fmaxf(oy, 0.f); }
        out16[(size_t)n * 50 + lane] = pack_bf16x2(ox, oy);
    }
}

// ---- fused mean-pool + linear head (R16-proven): 1 graph per 128-thr block ----
__global__ void pool_final_kernel(const unsigned* __restrict__ hb, const int* __restrict__ batch,
                                  const float* __restrict__ Wlin, const float* __restrict__ blin,
                                  float* __restrict__ out) {
    int g = blockIdx.x;
    int t = threadIdx.x;  // 128 = NUM_TASKS
    __shared__ float pl[HIDDEN];

    int lo = 0, hi = N_NODES;
    while (lo < hi) { int mid = (lo + hi) >> 1; if (batch[mid] < g) lo = mid + 1; else hi = mid; }
    int start = lo;
    hi = N_NODES;
    while (lo < hi) { int mid = (lo + hi) >> 1; if (batch[mid] < g + 1) lo = mid + 1; else hi = mid; }
    int end = lo;

    float inv = 1.0f / fmaxf((float)(end - start), 1.0f);
    if (t < 50) {
        float a0 = 0.f, a1 = 0.f;
        for (int n = start; n < end; ++n) {
            unsigned u = hb[(size_t)n * 50 + t];
            a0 += bf_lo(u); a1 += bf_hi(u);
        }
        pl[2 * t]     = a0 * inv;
        pl[2 * t + 1] = a1 * inv;
    }
    __syncthreads();

    float o = 0.f;
#pragma unroll 4
    for (int j = 0; j < HIDDEN; ++j) o += pl[j] * Wlin[j * NUM_TASKS + t];
    out[(size_t)g * NUM_TASKS + t] = o + blin[t];
}

extern "C" void kernel_launch(void* const* d_in, const int* in_sizes, int n_in,
                              void* d_out, int out_size, void* d_ws, size_t ws_size,
                              hipStream_t stream) {
    const int*   x     = (const int*)d_in[0];
    const int*   ei    = (const int*)d_in[1];
    const int*   batch = (const int*)d_in[2];
    const float* emb   = (const float*)d_in[3];
    const float* W1    = (const float*)d_in[4];
    const float* b1    = (const float*)d_in[5];
    const float* W2    = (const float*)d_in[6];
    const float* b2    = (const float*)d_in[7];
    const float* Wlin  = (const float*)d_in[8];
    const float* blin  = (const float*)d_in[9];
    float* out = (float*)d_out;

    const int* row = ei;             // edge_index[0] = source
    const int* col = ei + N_EDGES;   // edge_index[1] = target

    char* ws = (char*)d_ws;
    auto alloc = [&](size_t bytes) -> char* {
        char* p = ws;
        ws += (bytes + 255) & ~(size_t)255;
        return p;
    };
    int*      deg      = (int*)     alloc((size_t)N_NODES * 4);
    int*      cursor   = (int*)     alloc((size_t)N_NODES * 4);
    int*      csr_off  = (int*)     alloc((size_t)(N_NODES + 1) * 4);
    float*    dinv     = (float*)   alloc((size_t)N_NODES * 4);
    int2*     csr_pack = (int2*)    alloc((size_t)N_EDGES * 8);
    unsigned* bufP     = (unsigned*)alloc((size_t)N_NODES * 50 * 4);  // packed h0/h1/h2
    unsigned* hw16     = (unsigned*)alloc((size_t)N_NODES * 50 * 4);  // packed hw
    unsigned* wt1      = (unsigned*)alloc(112 * 64 * 4);              // bf16 W1^T tile
    unsigned* wt2      = (unsigned*)alloc(112 * 64 * 4);              // bf16 W2^T tile
    int*      bsum     = (int*)     alloc(256 * 4);

    hipMemsetAsync(deg, 0, (size_t)N_NODES * 4, stream);
    prep_kernel<<<DEG_BLOCKS + ENC_BLOCKS + WT_BLOCKS, 256, 0, stream>>>(
        col, deg, x, emb, bufP, W1, W2, wt1, wt2);
    blk_sum_kernel<<<SCAN_BLOCKS, 256, 0, stream>>>(deg, bsum);
    blk_scan_kernel<<<SCAN_BLOCKS, 256, 0, stream>>>(deg, bsum, csr_off, dinv, cursor);
    scatter_kernel<<<(N_EDGES + 255) / 256, 256, 0, stream>>>(row, col, csr_off, cursor, dinv,
                                                              csr_pack);

    // conv1: hw = bf16(h0 @ W1); agg -> relu -> h1 (packed bf16)
    mfma_matmul_kernel<<<MMGRID, 256, 0, stream>>>(bufP, wt1, (u16*)hw16);
    agg_kernel<<<(N_NODES + 3) / 4, 256, 0, stream>>>(hw16, csr_off, csr_pack,
                                                      dinv, deg, b1, bufP, 1);
    // conv2: hw = bf16(h1 @ W2); agg -> h2 (packed bf16)
    mfma_matmul_kernel<<<MMGRID, 256, 0, stream>>>(bufP, wt2, (u16*)hw16);
    agg_kernel<<<(N_NODES + 3) / 4, 256, 0, stream>>>(hw16, csr_off, csr_pack,
                                                      dinv, deg, b2, bufP, 0);

    pool_final_kernel<<<NUM_GRAPHS, 128, 0, stream>>>(bufP, batch, Wlin, blin, out);
}